// Round 5
// baseline (1384.527 us; speedup 1.0000x reference)
//
#include <hip/hip_runtime.h>

#define NN 500000
#define SH 9
#define NPB 512                          // nodes per bucket (1 << SH)
#define NBUCK ((NN + NPB - 1) / NPB)     // 977
#define PT_TILE 32768                    // edges per partition block
#define SENT (NN << SH)                  // sentinel packed edge: src=NN, nd=0

typedef _Float16 hf4 __attribute__((ext_vector_type(4)));
typedef _Float16 hf2 __attribute__((ext_vector_type(2)));

// ============================================================================
// Bucketed GCN, half tables, 8-way unrolled gathers (MLP):
//  1) k_bhist : per-bucket edge counts (LDS hist)
//  2) k_bscan : pad counts to x8, exclusive scan -> bbase, cur; zero g*[NN]
//  3) k_part  : partition edges; packed = (src<<9)|(dst&511), chunked writes
//  4) k_pad   : fill padding slots with SENT
//  5) k_deg   : per-bucket node counts (skip SENT) -> dis = rsqrt(deg+1)
//  6) k_xw    : g1 = half4( dis * (x @ W1) )
//  7) k_agg*  : per-bucket LDS SoA accumulation, 8 gathers in flight/thread,
//               fused epilogue h = tanh(dis*(acc+g_self)+b); g' = dis*(h@W)
// ============================================================================

__global__ __launch_bounds__(256) void k_bhist(const int* __restrict__ dst,
                                               int* __restrict__ bcount, int ne) {
    __shared__ int lh[NBUCK];
    for (int i = threadIdx.x; i < NBUCK; i += 256) lh[i] = 0;
    __syncthreads();
    int ne4 = ne >> 2;
    for (int i = blockIdx.x * 256 + threadIdx.x; i < ne4; i += gridDim.x * 256) {
        int4 d = ((const int4*)dst)[i];
        atomicAdd(&lh[d.x >> SH], 1);
        atomicAdd(&lh[d.y >> SH], 1);
        atomicAdd(&lh[d.z >> SH], 1);
        atomicAdd(&lh[d.w >> SH], 1);
    }
    if (blockIdx.x == 0) {
        for (int k = (ne & ~3) + threadIdx.x; k < ne; k += 256)
            atomicAdd(&lh[dst[k] >> SH], 1);
    }
    __syncthreads();
    for (int i = threadIdx.x; i < NBUCK; i += 256)
        if (lh[i]) atomicAdd(&bcount[i], lh[i]);
}

// pads each bucket count to a multiple of 8, scans, zeroes sentinel table rows
__global__ __launch_bounds__(1024) void k_bscan(const int* __restrict__ bcount,
                                                int* __restrict__ bbase,
                                                int* __restrict__ cur,
                                                hf4* __restrict__ g1,
                                                hf4* __restrict__ g2,
                                                hf2* __restrict__ g3) {
    __shared__ int sh[1024];
    int t = threadIdx.x;
    int v = (t < NBUCK) ? bcount[t] : 0;
    int pc = (v + 7) & ~7;
    sh[t] = pc;
    __syncthreads();
    for (int o = 1; o < 1024; o <<= 1) {
        int a = (t >= o) ? sh[t - o] : 0;
        __syncthreads();
        sh[t] += a;
        __syncthreads();
    }
    if (t < NBUCK) {
        int excl = sh[t] - pc;
        bbase[t] = excl;
        cur[t] = excl;
        if (t == NBUCK - 1) bbase[NBUCK] = sh[t];
    }
    if (t == 1023) {
        hf4 z4; z4.x = z4.y = z4.z = z4.w = (_Float16)0.f;
        hf2 z2; z2.x = z2.y = (_Float16)0.f;
        g1[NN] = z4; g2[NN] = z4; g3[NN] = z2;
    }
}

__global__ __launch_bounds__(256) void k_part(const int* __restrict__ src,
                                              const int* __restrict__ dst,
                                              int* __restrict__ cur,
                                              int* __restrict__ packed, int ne) {
    __shared__ int lhist[NBUCK];
    __shared__ int lcur[NBUCK];
    int tid = threadIdx.x;
    for (int i = tid; i < NBUCK; i += 256) lhist[i] = 0;
    __syncthreads();
    int t0 = blockIdx.x * PT_TILE;
    int t1 = t0 + PT_TILE; if (t1 > ne) t1 = ne;
    for (int e = t0 + tid * 4; e < t1; e += 1024) {
        if (e + 3 < t1) {
            int4 d = *(const int4*)(dst + e);
            atomicAdd(&lhist[d.x >> SH], 1);
            atomicAdd(&lhist[d.y >> SH], 1);
            atomicAdd(&lhist[d.z >> SH], 1);
            atomicAdd(&lhist[d.w >> SH], 1);
        } else {
            for (int k = e; k < t1; ++k) atomicAdd(&lhist[dst[k] >> SH], 1);
        }
    }
    __syncthreads();
    for (int i = tid; i < NBUCK; i += 256) {
        int c = lhist[i];
        lcur[i] = c ? atomicAdd(&cur[i], c) : 0;
    }
    __syncthreads();
    for (int e = t0 + tid * 4; e < t1; e += 1024) {
        if (e + 3 < t1) {
            int4 d = *(const int4*)(dst + e);
            int4 s = *(const int4*)(src + e);
            int b, p;
            b = d.x >> SH; p = atomicAdd(&lcur[b], 1); packed[p] = (s.x << SH) | (d.x & (NPB - 1));
            b = d.y >> SH; p = atomicAdd(&lcur[b], 1); packed[p] = (s.y << SH) | (d.y & (NPB - 1));
            b = d.z >> SH; p = atomicAdd(&lcur[b], 1); packed[p] = (s.z << SH) | (d.z & (NPB - 1));
            b = d.w >> SH; p = atomicAdd(&lcur[b], 1); packed[p] = (s.w << SH) | (d.w & (NPB - 1));
        } else {
            for (int k = e; k < t1; ++k) {
                int dd = dst[k], ss = src[k];
                int b = dd >> SH;
                int p = atomicAdd(&lcur[b], 1);
                packed[p] = (ss << SH) | (dd & (NPB - 1));
            }
        }
    }
}

// fill padding slots [cur[b], bbase[b+1]) with SENT
__global__ __launch_bounds__(1024) void k_pad(const int* __restrict__ cur,
                                              const int* __restrict__ bbase,
                                              int* __restrict__ packed) {
    int t = threadIdx.x;
    if (t < NBUCK) {
        int e = cur[t], e1 = bbase[t + 1];
        for (; e < e1; ++e) packed[e] = SENT;
    }
}

__global__ __launch_bounds__(1024) void k_deg(const int* __restrict__ bbase,
                                              const int* __restrict__ packed,
                                              float* __restrict__ dis) {
    __shared__ int cnt[NPB];
    int tid = threadIdx.x, b = blockIdx.x;
    for (int k = tid; k < NPB; k += 1024) cnt[k] = 0;
    __syncthreads();
    int e0 = bbase[b], e1 = bbase[b + 1];
    for (int e = e0 + (tid << 3); e + 8 <= e1; e += 8192) {
        const int4* pp = (const int4*)(packed + e);
        int4 pa = pp[0], pb = pp[1];
        if (pa.x != SENT) atomicAdd(&cnt[pa.x & (NPB - 1)], 1);
        if (pa.y != SENT) atomicAdd(&cnt[pa.y & (NPB - 1)], 1);
        if (pa.z != SENT) atomicAdd(&cnt[pa.z & (NPB - 1)], 1);
        if (pa.w != SENT) atomicAdd(&cnt[pa.w & (NPB - 1)], 1);
        if (pb.x != SENT) atomicAdd(&cnt[pb.x & (NPB - 1)], 1);
        if (pb.y != SENT) atomicAdd(&cnt[pb.y & (NPB - 1)], 1);
        if (pb.z != SENT) atomicAdd(&cnt[pb.z & (NPB - 1)], 1);
        if (pb.w != SENT) atomicAdd(&cnt[pb.w & (NPB - 1)], 1);
    }
    __syncthreads();
    int i0 = b << SH;
    for (int k = tid; k < NPB; k += 1024) {
        int i = i0 + k;
        if (i < NN) dis[i] = rsqrtf((float)cnt[k] + 1.0f);
    }
}

// g1 = half4( dis * (x @ W1) ), wave per row
__global__ __launch_bounds__(256) void k_xw(const float* __restrict__ x,
                                            const float* __restrict__ W1,
                                            const float* __restrict__ dis,
                                            hf4* __restrict__ g, int n) {
    __shared__ float4 sW[128];
    int tid = threadIdx.x;
    if (tid < 128) sW[tid] = ((const float4*)W1)[tid];
    __syncthreads();
    int wave = tid >> 6, lane = tid & 63;
    int row = blockIdx.x * 4 + wave;
    if (row >= n) return;
    float2 xv = ((const float2*)(x + (size_t)row * 128))[lane];
    float4 w0 = sW[2 * lane], w1 = sW[2 * lane + 1];
    float a0 = xv.x * w0.x + xv.y * w1.x;
    float a1 = xv.x * w0.y + xv.y * w1.y;
    float a2 = xv.x * w0.z + xv.y * w1.z;
    float a3 = xv.x * w0.w + xv.y * w1.w;
    for (int off = 32; off; off >>= 1) {
        a0 += __shfl_xor(a0, off);
        a1 += __shfl_xor(a1, off);
        a2 += __shfl_xor(a2, off);
        a3 += __shfl_xor(a3, off);
    }
    if (lane == 0) {
        float dv = dis[row];
        hf4 o;
        o.x = (_Float16)(dv * a0); o.y = (_Float16)(dv * a1);
        o.z = (_Float16)(dv * a2); o.w = (_Float16)(dv * a3);
        g[row] = o;
    }
}

#define ACC4(v, nd)                                   \
    unsafeAtomicAdd(&acc[0][nd], (float)(v).x);       \
    unsafeAtomicAdd(&acc[1][nd], (float)(v).y);       \
    unsafeAtomicAdd(&acc[2][nd], (float)(v).z);       \
    unsafeAtomicAdd(&acc[3][nd], (float)(v).w);

// layer: gin hf4 -> gout hf4 via W (4x4 row-major), bias
__global__ __launch_bounds__(1024) void k_agg44(const int* __restrict__ bbase,
                                                const int* __restrict__ packed,
                                                const hf4* __restrict__ gin,
                                                const float* __restrict__ dis,
                                                const float* __restrict__ bias,
                                                const float* __restrict__ W,
                                                hf4* __restrict__ gout) {
    __shared__ float acc[4][NPB];
    int tid = threadIdx.x, b = blockIdx.x;
    for (int k = tid; k < NPB; k += 1024) {
        acc[0][k] = 0.f; acc[1][k] = 0.f; acc[2][k] = 0.f; acc[3][k] = 0.f;
    }
    __syncthreads();
    int e0 = bbase[b], e1 = bbase[b + 1];
    for (int e = e0 + (tid << 3); e + 8 <= e1; e += 8192) {
        const int4* pp = (const int4*)(packed + e);
        int4 pa = pp[0], pb = pp[1];
        hf4 v0 = gin[(unsigned)pa.x >> SH];
        hf4 v1 = gin[(unsigned)pa.y >> SH];
        hf4 v2 = gin[(unsigned)pa.z >> SH];
        hf4 v3 = gin[(unsigned)pa.w >> SH];
        hf4 v4 = gin[(unsigned)pb.x >> SH];
        hf4 v5 = gin[(unsigned)pb.y >> SH];
        hf4 v6 = gin[(unsigned)pb.z >> SH];
        hf4 v7 = gin[(unsigned)pb.w >> SH];
        ACC4(v0, pa.x & (NPB - 1)); ACC4(v1, pa.y & (NPB - 1));
        ACC4(v2, pa.z & (NPB - 1)); ACC4(v3, pa.w & (NPB - 1));
        ACC4(v4, pb.x & (NPB - 1)); ACC4(v5, pb.y & (NPB - 1));
        ACC4(v6, pb.z & (NPB - 1)); ACC4(v7, pb.w & (NPB - 1));
    }
    __syncthreads();
    int i0 = b << SH;
    for (int k = tid; k < NPB; k += 1024) {
        int i = i0 + k;
        if (i >= NN) continue;
        float dv = dis[i];
        hf4 gs = gin[i];
        float h0 = tanhf(dv * (acc[0][k] + (float)gs.x) + bias[0]);
        float h1 = tanhf(dv * (acc[1][k] + (float)gs.y) + bias[1]);
        float h2 = tanhf(dv * (acc[2][k] + (float)gs.z) + bias[2]);
        float h3 = tanhf(dv * (acc[3][k] + (float)gs.w) + bias[3]);
        hf4 o;
        o.x = (_Float16)(dv * (h0 * W[0] + h1 * W[4] + h2 * W[8]  + h3 * W[12]));
        o.y = (_Float16)(dv * (h0 * W[1] + h1 * W[5] + h2 * W[9]  + h3 * W[13]));
        o.z = (_Float16)(dv * (h0 * W[2] + h1 * W[6] + h2 * W[10] + h3 * W[14]));
        o.w = (_Float16)(dv * (h0 * W[3] + h1 * W[7] + h2 * W[11] + h3 * W[15]));
        gout[i] = o;
    }
}

// layer: gin hf4 -> gout hf2 via W (4x2 row-major), bias
__global__ __launch_bounds__(1024) void k_agg42(const int* __restrict__ bbase,
                                                const int* __restrict__ packed,
                                                const hf4* __restrict__ gin,
                                                const float* __restrict__ dis,
                                                const float* __restrict__ bias,
                                                const float* __restrict__ W,
                                                hf2* __restrict__ gout) {
    __shared__ float acc[4][NPB];
    int tid = threadIdx.x, b = blockIdx.x;
    for (int k = tid; k < NPB; k += 1024) {
        acc[0][k] = 0.f; acc[1][k] = 0.f; acc[2][k] = 0.f; acc[3][k] = 0.f;
    }
    __syncthreads();
    int e0 = bbase[b], e1 = bbase[b + 1];
    for (int e = e0 + (tid << 3); e + 8 <= e1; e += 8192) {
        const int4* pp = (const int4*)(packed + e);
        int4 pa = pp[0], pb = pp[1];
        hf4 v0 = gin[(unsigned)pa.x >> SH];
        hf4 v1 = gin[(unsigned)pa.y >> SH];
        hf4 v2 = gin[(unsigned)pa.z >> SH];
        hf4 v3 = gin[(unsigned)pa.w >> SH];
        hf4 v4 = gin[(unsigned)pb.x >> SH];
        hf4 v5 = gin[(unsigned)pb.y >> SH];
        hf4 v6 = gin[(unsigned)pb.z >> SH];
        hf4 v7 = gin[(unsigned)pb.w >> SH];
        ACC4(v0, pa.x & (NPB - 1)); ACC4(v1, pa.y & (NPB - 1));
        ACC4(v2, pa.z & (NPB - 1)); ACC4(v3, pa.w & (NPB - 1));
        ACC4(v4, pb.x & (NPB - 1)); ACC4(v5, pb.y & (NPB - 1));
        ACC4(v6, pb.z & (NPB - 1)); ACC4(v7, pb.w & (NPB - 1));
    }
    __syncthreads();
    int i0 = b << SH;
    for (int k = tid; k < NPB; k += 1024) {
        int i = i0 + k;
        if (i >= NN) continue;
        float dv = dis[i];
        hf4 gs = gin[i];
        float h0 = tanhf(dv * (acc[0][k] + (float)gs.x) + bias[0]);
        float h1 = tanhf(dv * (acc[1][k] + (float)gs.y) + bias[1]);
        float h2 = tanhf(dv * (acc[2][k] + (float)gs.z) + bias[2]);
        float h3 = tanhf(dv * (acc[3][k] + (float)gs.w) + bias[3]);
        hf2 o;
        o.x = (_Float16)(dv * (h0 * W[0] + h1 * W[2] + h2 * W[4] + h3 * W[6]));
        o.y = (_Float16)(dv * (h0 * W[1] + h1 * W[3] + h2 * W[5] + h3 * W[7]));
        gout[i] = o;
    }
}

// final layer: gin hf2 -> h=tanh(...), out = h@Wc + bc ; writes out f4 + hout f2
__global__ __launch_bounds__(1024) void k_agg2out(const int* __restrict__ bbase,
                                                  const int* __restrict__ packed,
                                                  const hf2* __restrict__ gin,
                                                  const float* __restrict__ dis,
                                                  const float* __restrict__ b3,
                                                  const float* __restrict__ Wc,
                                                  const float* __restrict__ bc,
                                                  float4* __restrict__ out,
                                                  float2* __restrict__ hout) {
    __shared__ float acc[2][NPB];
    int tid = threadIdx.x, b = blockIdx.x;
    for (int k = tid; k < NPB; k += 1024) { acc[0][k] = 0.f; acc[1][k] = 0.f; }
    __syncthreads();
    int e0 = bbase[b], e1 = bbase[b + 1];
    for (int e = e0 + (tid << 3); e + 8 <= e1; e += 8192) {
        const int4* pp = (const int4*)(packed + e);
        int4 pa = pp[0], pb = pp[1];
        hf2 v0 = gin[(unsigned)pa.x >> SH];
        hf2 v1 = gin[(unsigned)pa.y >> SH];
        hf2 v2 = gin[(unsigned)pa.z >> SH];
        hf2 v3 = gin[(unsigned)pa.w >> SH];
        hf2 v4 = gin[(unsigned)pb.x >> SH];
        hf2 v5 = gin[(unsigned)pb.y >> SH];
        hf2 v6 = gin[(unsigned)pb.z >> SH];
        hf2 v7 = gin[(unsigned)pb.w >> SH];
        int n0, n1;
        n0 = pa.x & (NPB - 1); unsafeAtomicAdd(&acc[0][n0], (float)v0.x); unsafeAtomicAdd(&acc[1][n0], (float)v0.y);
        n1 = pa.y & (NPB - 1); unsafeAtomicAdd(&acc[0][n1], (float)v1.x); unsafeAtomicAdd(&acc[1][n1], (float)v1.y);
        n0 = pa.z & (NPB - 1); unsafeAtomicAdd(&acc[0][n0], (float)v2.x); unsafeAtomicAdd(&acc[1][n0], (float)v2.y);
        n1 = pa.w & (NPB - 1); unsafeAtomicAdd(&acc[0][n1], (float)v3.x); unsafeAtomicAdd(&acc[1][n1], (float)v3.y);
        n0 = pb.x & (NPB - 1); unsafeAtomicAdd(&acc[0][n0], (float)v4.x); unsafeAtomicAdd(&acc[1][n0], (float)v4.y);
        n1 = pb.y & (NPB - 1); unsafeAtomicAdd(&acc[0][n1], (float)v5.x); unsafeAtomicAdd(&acc[1][n1], (float)v5.y);
        n0 = pb.z & (NPB - 1); unsafeAtomicAdd(&acc[0][n0], (float)v6.x); unsafeAtomicAdd(&acc[1][n0], (float)v6.y);
        n1 = pb.w & (NPB - 1); unsafeAtomicAdd(&acc[0][n1], (float)v7.x); unsafeAtomicAdd(&acc[1][n1], (float)v7.y);
    }
    __syncthreads();
    int i0 = b << SH;
    for (int k = tid; k < NPB; k += 1024) {
        int i = i0 + k;
        if (i >= NN) continue;
        float dv = dis[i];
        hf2 gs = gin[i];
        float h0 = tanhf(dv * (acc[0][k] + (float)gs.x) + b3[0]);
        float h1 = tanhf(dv * (acc[1][k] + (float)gs.y) + b3[1]);
        float4 o;
        o.x = h0 * Wc[0] + h1 * Wc[4] + bc[0];
        o.y = h0 * Wc[1] + h1 * Wc[5] + bc[1];
        o.z = h0 * Wc[2] + h1 * Wc[6] + bc[2];
        o.w = h0 * Wc[3] + h1 * Wc[7] + bc[3];
        out[i] = o;
        hout[i] = make_float2(h0, h1);
    }
}

extern "C" void kernel_launch(void* const* d_in, const int* in_sizes, int n_in,
                              void* d_out, int out_size, void* d_ws, size_t ws_size,
                              hipStream_t stream) {
    const float* x  = (const float*)d_in[0];
    const int*   ei = (const int*)d_in[1];
    const float* W1 = (const float*)d_in[2];
    const float* b1 = (const float*)d_in[3];
    const float* W2 = (const float*)d_in[4];
    const float* b2 = (const float*)d_in[5];
    const float* W3 = (const float*)d_in[6];
    const float* b3 = (const float*)d_in[7];
    const float* Wc = (const float*)d_in[8];
    const float* bc = (const float*)d_in[9];

    const int n  = NN;
    const int ne = in_sizes[1] / 2;
    const int* src  = ei;
    const int* dstp = ei + ne;

    const int cap = ne + 8 * NBUCK;   // padded edge capacity

    // workspace (bytes):
    // packed[cap] | dis[n] | g1(hf4)[n+1] | g2(hf4)[n+1] | g3(hf2)[n+1] | bcount|bbase|cur
    char* base = (char*)d_ws;
    int*   packed = (int*)base;                       base += ((size_t)cap * 4 + 15) & ~15ull;
    float* dis    = (float*)base;                     base += (size_t)n * 4;
    hf4*   g1     = (hf4*)base;                       base += ((size_t)n + 1) * 8;
    hf4*   g2     = (hf4*)base;                       base += ((size_t)n + 1) * 8;
    hf2*   g3     = (hf2*)base;                       base += (((size_t)n + 1) * 4 + 15) & ~15ull;
    int*   bcount = (int*)base;                       base += (NBUCK + 1) * 4;
    int*   bbase  = (int*)base;                       base += (NBUCK + 1) * 4;
    int*   cur    = (int*)base;

    float4* out4  = (float4*)d_out;
    float2* hout2 = (float2*)((float*)d_out + 4 * (size_t)n);

    hipMemsetAsync(bcount, 0, (NBUCK + 1) * 4, stream);
    k_bhist<<<512, 256, 0, stream>>>(dstp, bcount, ne);
    k_bscan<<<1, 1024, 0, stream>>>(bcount, bbase, cur, g1, g2, g3);
    k_part<<<(ne + PT_TILE - 1) / PT_TILE, 256, 0, stream>>>(src, dstp, cur, packed, ne);
    k_pad<<<1, 1024, 0, stream>>>(cur, bbase, packed);
    k_deg<<<NBUCK, 1024, 0, stream>>>(bbase, packed, dis);
    k_xw<<<(n + 3) / 4, 256, 0, stream>>>(x, W1, dis, g1, n);
    k_agg44<<<NBUCK, 1024, 0, stream>>>(bbase, packed, g1, dis, b1, W2, g2);
    k_agg42<<<NBUCK, 1024, 0, stream>>>(bbase, packed, g2, dis, b2, W3, g3);
    k_agg2out<<<NBUCK, 1024, 0, stream>>>(bbase, packed, g3, dis, b3, Wc, bc,
                                          out4, hout2);
}